// Round 7
// baseline (249.722 us; speedup 1.0000x reference)
//
#include <hip/hip_runtime.h>
#include <hip/hip_fp16.h>

// ---------------------------------------------------------------------------
// GCN: h1 = relu(Agg(x@W1)+b1); h2 = relu(Agg(h1@W2)+b2); out = h2@Wfc+bfc
// Agg(h)[i] = sum_{e: dst[e]==i} dinv[src]*w*dinv[i] * h[src] + dinv[i]^2*h[i]
// R1..R5: scan->packed-atomic->fp16->batched-gather->MFMA (553->259us).
// R7: direct bucketing, 1 returning atomic + 8B scatter per edge (242us).
// R8/R9/R10: bucket is a ~7.4 returning-atomic/cy fabric ceiling,
// independent of occupancy/MLP/address spread.
// R11/R12: two-phase binning killed the atomics (244->211us CONFIRMED).
//   P1 (fused under gemm1): bin 4096 edges/block by dst>>8; LDS-atomic
//   ranks; ONE global atomic per (block,bin) -> ~38k returning atomics.
//   P2 k_build: coalesced bucket read, LDS-cursor scatter, cnt+dinv direct.
// R13 REGRESSED (211->234): agg+gemm fusion at 256 threads = 3128 waves x
// 16 serial nodes -> occupancy 26%, latency-bound gathers starved of TLP.
// R14: same fusion, 1024-thread blocks (16 waves): wave w aggs 4 nodes
// (w*4+r), 12512 waves chip-wide, LDS 17.4KB -> 2 blocks/CU = 32 waves/CU.
// Gemm phase splits the 64x128 tile 16 ways: rowgroup=w>>2, colpair=w&3
// (2 of 8 col-tiles each, 8 MFMAs/wave). Keeps R13's wins: no bufA
// round-trip, 2 fewer dispatches, MFMA overlaps other blocks' gathers.
// Packing requires N < 65536 (N=50000).
// ---------------------------------------------------------------------------

typedef unsigned long long u64;
typedef _Float16 f16x8 __attribute__((ext_vector_type(8)));
typedef float f32x4 __attribute__((ext_vector_type(4)));

#define CAP 96        // max degree slack: Poisson(16) max over 50k nodes is ~45
#define CREG 5120     // coarse region per bucket: mean 4096, sigma 64, +16 sigma

// zero bucket cursors + transpose/convert 3 weights fp32[k][n] -> fp16 Wt[n][k]
__global__ __launch_bounds__(256) void k_pre(unsigned* gcur,
                                             const float* __restrict__ W1,
                                             const float* __restrict__ W2,
                                             const float* __restrict__ Wfc,
                                             __half* __restrict__ Wt) {
    int i = blockIdx.x * 256 + threadIdx.x;
    if (i < 256) gcur[i] = 0u;
    if (i < 3 * 16384) {
        int w = i >> 14, r = i & 16383;
        int nn = r >> 7, kk = r & 127;
        const float* W = (w == 0) ? W1 : (w == 1) ? W2 : Wfc;
        Wt[i] = __float2half(W[kk * 128 + nn]);
    }
}

// LDS-free gemm1 body (R9): B-fragments read straight from global Wt
// (32KB, L1/L2-broadcast across blocks). A: X[m=lane&15][k=quad*8+j];
// C: row=quad*4+reg, col=lane&15. fp32 accumulate.
__device__ __forceinline__ void gemm1_body_nolds(int bx,
                                                 const float* __restrict__ X,
                                                 const __half* __restrict__ Wt,
                                                 __half* __restrict__ Y, int n) {
    int t = threadIdx.x;
    int wave = t >> 6, lane = t & 63;
    int quad = lane >> 4, fcol = lane & 15;
    int rowbase = bx * 64 + wave * 16;
    int arow = rowbase + fcol;

    f16x8 a[4];
#pragma unroll
    for (int c = 0; c < 4; c++) {
        int k0 = c * 32 + quad * 8;
        if (arow < n) {
            const float* p = X + (size_t)arow * 128 + k0;
#pragma unroll
            for (int j = 0; j < 8; j++) a[c][j] = (_Float16)p[j];
        } else {
            f16x8 z = {0, 0, 0, 0, 0, 0, 0, 0};
            a[c] = z;
        }
    }

    f32x4 acc[8];
#pragma unroll
    for (int c = 0; c < 8; c++) acc[c] = (f32x4){0.f, 0.f, 0.f, 0.f};

#pragma unroll
    for (int kc = 0; kc < 4; kc++) {
        int k0 = kc * 32 + quad * 8;
#pragma unroll
        for (int ct = 0; ct < 8; ct++) {
            f16x8 b = *(const f16x8*)((const _Float16*)Wt +
                                      (size_t)(ct * 16 + fcol) * 128 + k0);
            acc[ct] = __builtin_amdgcn_mfma_f32_16x16x32_f16(a[kc], b, acc[ct], 0, 0, 0);
        }
    }

#pragma unroll
    for (int reg = 0; reg < 4; reg++) {
        int gr = rowbase + quad * 4 + reg;
        if (gr < n) {
#pragma unroll
            for (int ct = 0; ct < 8; ct++)
                Y[(size_t)gr * 128 + ct * 16 + fcol] = __float2half(acc[ct][reg]);
        }
    }
}

// Phase 1: coarse-bin 4096 edges/block by dst>>8. LDS atomics give each
// edge its intra-block rank per bin; ONE global atomic per (block,bin)
// reserves a contiguous run; records written at base+rank (same-bin runs
// contiguous -> L2 line-merge).
// Record: bits[0:8)=dst&255, [8:24)=src (N<65536), [32:64)=w bits.
__device__ __forceinline__ void p1_body(int bx, const int* __restrict__ src,
                                        const int* __restrict__ dst,
                                        const float* __restrict__ ew,
                                        unsigned* __restrict__ gcur,
                                        u64* __restrict__ coarse, int E, int NB) {
    __shared__ unsigned lcb[256];    // per-bin count, then per-bin global base
    int t = threadIdx.x;
    lcb[t] = 0u;
    __syncthreads();

    u64 rec[16];
    unsigned br[16];                 // (bin<<16) | rank
    int e0 = bx * 4096 + t;
#pragma unroll
    for (int k = 0; k < 16; k++) {
        int e = e0 + k * 256;
        if (e < E) {
            int d = dst[e];
            int s = src[e];
            unsigned wb = __float_as_uint(ew[e]);
            int bin = d >> 8;
            unsigned r = atomicAdd(&lcb[bin], 1u);   // LDS atomic
            rec[k] = ((u64)wb << 32) | ((u64)((unsigned)s << 8)) | (u64)(d & 255);
            br[k] = ((unsigned)bin << 16) | r;       // rank < 4096 fits
        } else {
            br[k] = 0xFFFFFFFFu;
        }
    }
    __syncthreads();
    if (t < NB) {
        unsigned c = lcb[t];
        unsigned base = c ? atomicAdd(&gcur[t], c) : 0u;  // 1 global atomic/bin
        lcb[t] = base;
    }
    __syncthreads();
#pragma unroll
    for (int k = 0; k < 16; k++) {
        if (br[k] != 0xFFFFFFFFu) {
            int bin = br[k] >> 16;
            unsigned pos = lcb[bin] + (br[k] & 0xFFFFu);
            if (pos < CREG)
                coarse[(size_t)bin * CREG + pos] = rec[k];
        }
    }
}

// Fused launch: blocks [0,GB) = LDS-free gemm1, blocks [GB, GB+p1b) = P1.
__global__ __launch_bounds__(256) void k_gemm1_p1(
    const float* __restrict__ x, const __half* __restrict__ Wt,
    __half* __restrict__ bufH, int n, int GB,
    const int* __restrict__ src, const int* __restrict__ dst,
    const float* __restrict__ ew, unsigned* __restrict__ gcur,
    u64* __restrict__ coarse, int E, int NB) {
    int bx = blockIdx.x;
    if (bx < GB) {
        gemm1_body_nolds(bx, x, Wt, bufH, n);
        return;
    }
    p1_body(bx - GB, src, dst, ew, gcur, coarse, E, NB);
}

// Phase 2: one block per bucket (256 nodes). Coalesced read of the bucket's
// records; LDS cursors (no global atomics) scatter into slots; LDS float
// sums -> cnt + dinv written directly.
__global__ __launch_bounds__(256) void k_build(const u64* __restrict__ coarse,
                                               const unsigned* __restrict__ gcur,
                                               int2* __restrict__ slots,
                                               unsigned* __restrict__ cnt,
                                               float* __restrict__ dinv,
                                               int n) {
    __shared__ unsigned lcnt[256];
    __shared__ float lws[256];
    int b = blockIdx.x, t = threadIdx.x;
    lcnt[t] = 0u;
    lws[t] = 0.f;
    __syncthreads();
    int ec = min((int)gcur[b], CREG);
    const u64* reg = coarse + (size_t)b * CREG;
    int nb0 = b << 8;
    for (int e = t; e < ec; e += 256) {
        u64 r = reg[e];
        int dloc = (int)(r & 255u);
        int s = (int)((r >> 8) & 0xFFFFu);
        unsigned wb = (unsigned)(r >> 32);
        unsigned pos = atomicAdd(&lcnt[dloc], 1u);        // LDS atomic
        atomicAdd(&lws[dloc], __uint_as_float(wb));       // LDS float atomic
        if (pos < CAP)
            slots[(size_t)(nb0 + dloc) * CAP + pos] = make_int2(s, (int)wb);
    }
    __syncthreads();
    int node = nb0 + t;
    if (node < n) {
        cnt[node] = lcnt[t];
        dinv[node] = rsqrtf(1.0f + lws[t]);
    }
}

// R14 fused agg+gemm, 1024 threads = 16 waves per 64-row block.
// Agg phase: wave w aggs nodes rowbase+w*4+r (r=0..3), proven coop-load +
// shfl-broadcast inner loop, bias_pre + ReLU, rows -> LDS A-tile. Barrier.
// Gemm phase: rowgroup g=w>>2 (16 rows), colpair cg=w&3 (ct in {2cg,2cg+1});
// A from LDS, B from global Wt. OUT_HALF: fp16 rows | fp32 + bias_post.
template <bool OUT_HALF>
__global__ __launch_bounds__(1024) void k_agg_gemm(
    const __half* __restrict__ H, const int2* __restrict__ slots,
    const unsigned* __restrict__ cnt, const float* __restrict__ dinv,
    const float* __restrict__ bias_pre, const __half* __restrict__ Wt,
    const float* __restrict__ bias_post, void* __restrict__ Yv, int n) {
    __shared__ __align__(16) _Float16 As[64][136];
    int t = threadIdx.x, wave = t >> 6, lane = t & 63;
    int rowbase = blockIdx.x * 64;

    float2 bpre = ((const float2*)bias_pre)[lane];

    for (int r = 0; r < 4; ++r) {
        int i = __builtin_amdgcn_readfirstlane(rowbase + wave * 4 + r);
        float ax = 0.f, ay = 0.f;
        if (i < n) {
            float di = dinv[i];
            float2 h0 = __half22float2(((const __half2*)(H + (size_t)i * 128))[lane]);
            ax = di * di * h0.x;
            ay = di * di * h0.y;
            int c = min((int)cnt[i], CAP);
            const int2* row = slots + (size_t)i * CAP;

            for (int base = 0; base < c; base += 64) {
                int cnt2 = min(64, c - base);
                int mys = 0; float myv = 0.f;
                if (lane < cnt2) {
                    int2 pr = row[base + lane];
                    mys = pr.x;
                    myv = dinv[pr.x] * __int_as_float(pr.y) * di;
                }
                int j = 0;
                for (; j + 16 <= cnt2; j += 16) {
                    float2 h[16];
                    float v[16];
#pragma unroll
                    for (int u = 0; u < 16; u++) {
                        int s = __shfl(mys, j + u);
                        v[u] = __shfl(myv, j + u);
                        h[u] = __half22float2(((const __half2*)(H + (size_t)s * 128))[lane]);
                    }
#pragma unroll
                    for (int u = 0; u < 16; u++) {
                        ax = fmaf(v[u], h[u].x, ax);
                        ay = fmaf(v[u], h[u].y, ay);
                    }
                }
                for (; j < cnt2; j += 8) {   // masked batches: no serial tail
                    float2 h[8];
                    float v[8];
#pragma unroll
                    for (int u = 0; u < 8; u++) {
                        int idx = j + u;
                        int lsrc = min(idx, cnt2 - 1);
                        int s = __shfl(mys, lsrc);
                        float tv = __shfl(myv, lsrc);
                        v[u] = (idx < cnt2) ? tv : 0.f;
                        h[u] = __half22float2(((const __half2*)(H + (size_t)s * 128))[lane]);
                    }
#pragma unroll
                    for (int u = 0; u < 8; u++) {
                        ax = fmaf(v[u], h[u].x, ax);
                        ay = fmaf(v[u], h[u].y, ay);
                    }
                }
            }
            ax = fmaxf(ax + bpre.x, 0.f);
            ay = fmaxf(ay + bpre.y, 0.f);
        }
        // store the relu'd row into the LDS A-tile (lane -> 4B, conflict-free)
        __half2 hv = __floats2half2_rn(ax, ay);
        *(__half2*)&As[wave * 4 + r][lane * 2] = hv;
    }
    __syncthreads();

    // gemm phase: 16 waves cover the 64x128 C-tile.
    // wave -> (rowgroup g = wave>>2, colpair cg = wave&3): rows g*16..+15,
    // col-tiles ct in {2cg, 2cg+1}. A from LDS, B from global Wt.
    int quad = lane >> 4, fcol = lane & 15;
    int g = wave >> 2, cg = wave & 3;
    f16x8 a[4];
#pragma unroll
    for (int c = 0; c < 4; c++)
        a[c] = *(const f16x8*)&As[g * 16 + fcol][c * 32 + quad * 8];

    f32x4 acc[2];
#pragma unroll
    for (int c = 0; c < 2; c++) acc[c] = (f32x4){0.f, 0.f, 0.f, 0.f};

#pragma unroll
    for (int kc = 0; kc < 4; kc++) {
        int k0 = kc * 32 + quad * 8;
#pragma unroll
        for (int cc = 0; cc < 2; cc++) {
            int ct = cg * 2 + cc;
            f16x8 b = *(const f16x8*)((const _Float16*)Wt +
                                      (size_t)(ct * 16 + fcol) * 128 + k0);
            acc[cc] = __builtin_amdgcn_mfma_f32_16x16x32_f16(a[kc], b, acc[cc], 0, 0, 0);
        }
    }

    int rb2 = rowbase + g * 16;
#pragma unroll
    for (int reg = 0; reg < 4; reg++) {
        int gr = rb2 + quad * 4 + reg;
        if (gr < n) {
            if (OUT_HALF) {
                __half* Y = (__half*)Yv;
#pragma unroll
                for (int cc = 0; cc < 2; cc++) {
                    int ct = cg * 2 + cc;
                    Y[(size_t)gr * 128 + ct * 16 + fcol] = __float2half(acc[cc][reg]);
                }
            } else {
                float* Y = (float*)Yv;
#pragma unroll
                for (int cc = 0; cc < 2; cc++) {
                    int ct = cg * 2 + cc;
                    Y[(size_t)gr * 128 + ct * 16 + fcol] =
                        acc[cc][reg] + bias_post[ct * 16 + fcol];
                }
            }
        }
    }
}

extern "C" void kernel_launch(void* const* d_in, const int* in_sizes, int n_in,
                              void* d_out, int out_size, void* d_ws, size_t ws_size,
                              hipStream_t stream) {
    const float* x   = (const float*)d_in[0];
    const float* ew  = (const float*)d_in[1];
    const float* W1  = (const float*)d_in[2];
    const float* b1  = (const float*)d_in[3];
    const float* W2  = (const float*)d_in[4];
    const float* b2  = (const float*)d_in[5];
    const float* Wfc = (const float*)d_in[6];
    const float* bfc = (const float*)d_in[7];
    const int* eidx  = (const int*)d_in[8];

    const int E = in_sizes[1];
    const int N = in_sizes[0] / 128;
    const int* src = eidx;       // edge_index row 0
    const int* dst = eidx + E;   // edge_index row 1

    char* ws = (char*)d_ws;
    size_t off = 0;
    auto alloc = [&](size_t bytes) -> void* {
        void* p = ws + off;
        off = (off + bytes + 255) & ~(size_t)255;
        return p;
    };
    int gb  = (N + 63) / 64;             // 64-row tiles (gemm1 + fused agg_gemm)
    int p1b = (E + 4095) / 4096;         // P1: 4096 edges/block
    int NB  = (N + 255) >> 8;            // coarse buckets of 256 nodes
    int pb  = (3 * 16384 + 255) / 256;
    int Npad = N + 64;

    unsigned* gcur = (unsigned*)alloc(256 * 4);
    unsigned* cnt  = (unsigned*)alloc((size_t)N * 4);
    float*  dinv   = (float*)alloc((size_t)N * 4);
    u64*    coarse = (u64*)alloc((size_t)NB * CREG * 8);
    int2*   slots  = (int2*)alloc((size_t)N * CAP * 8);
    __half* Wt     = (__half*)alloc((size_t)3 * 16384 * 2);  // 3 fp16 [n][k]
    __half* bufH   = (__half*)alloc((size_t)Npad * 128 * 2); // gemm1 output
    __half* bufH2  = (__half*)alloc((size_t)Npad * 128 * 2); // agg_gemm<true> out

    // Prep: zero cursors + weight transpose; then gemm1 fused with P1.
    k_pre<<<pb, 256, 0, stream>>>(gcur, W1, W2, Wfc, Wt);
    k_gemm1_p1<<<gb + p1b, 256, 0, stream>>>(x, Wt, bufH, N, gb,
                                             src, dst, ew, gcur, coarse, E, NB);
    k_build<<<NB, 256, 0, stream>>>(coarse, gcur, slots, cnt, dinv, N);

    // Layer 1 agg + layer 2 GEMM fused; layer 2 agg + FC fused (16 waves).
    k_agg_gemm<true><<<gb, 1024, 0, stream>>>(bufH, slots, cnt, dinv, b1,
                                              Wt + 16384, nullptr, bufH2, N);
    k_agg_gemm<false><<<gb, 1024, 0, stream>>>(bufH2, slots, cnt, dinv, b2,
                                               Wt + 2 * 16384, bfc, d_out, N);
}

// Round 8
// 211.475 us; speedup vs baseline: 1.1809x; 1.1809x over previous
//
#include <hip/hip_runtime.h>
#include <hip/hip_fp16.h>

// ---------------------------------------------------------------------------
// GCN: h1 = relu(Agg(x@W1)+b1); h2 = relu(Agg(h1@W2)+b2); out = h2@Wfc+bfc
// Agg(h)[i] = sum_{e: dst[e]==i} dinv[src]*w*dinv[i] * h[src] + dinv[i]^2*h[i]
// R1..R5: scan->packed-atomic->fp16->batched-gather->MFMA (553->259us).
// R7: direct bucketing, 1 returning atomic + 8B scatter per edge (242us).
// R8/R9/R10: bucket = ~7.4 returning-atomic/cy fabric ceiling, independent
// of occupancy/MLP/address spread.
// R11/R12: two-phase binning killed the atomics (244->211us CONFIRMED):
//   P1 (fused under gemm1) bins edges by dst>>8 with LDS-atomic ranks +
//   ONE global atomic per (block,bin); P2 k_build scatters via LDS cursors.
// R13 REGRESSED (211->234): agg+gemm fusion, 256thr: 16x less TLP for the
// latency-bound gathers (occupancy 26%).
// R14 REGRESSED (234->250): same at 1024thr: VGPR squeezed to 36 ->
// gather batch spills to scratch. CONCLUSION: fusion trades away the
// split-agg's 50k-wave oversubscription + register headroom; abandoned.
// R15: revert to R12 split structure; k_agg gathers TWO rows per
// instruction (lanes 0-31 row e0, lanes 32-63 row e1, 8B/lane): halves
// gather-instruction count + shfl->load chains at same bytes/FMAs.
// Final 4x shfl_xor(32) merges the edge-halves.
// Packing requires N < 65536 (N=50000).
// ---------------------------------------------------------------------------

typedef unsigned long long u64;
typedef _Float16 f16x8 __attribute__((ext_vector_type(8)));
typedef float f32x4 __attribute__((ext_vector_type(4)));

#define CAP 96        // max degree slack: Poisson(16) max over 50k nodes is ~45
#define CREG 5120     // coarse region per bucket: mean 4096, sigma 64, +16 sigma

// zero bucket cursors + transpose/convert 3 weights fp32[k][n] -> fp16 Wt[n][k]
__global__ __launch_bounds__(256) void k_pre(unsigned* gcur,
                                             const float* __restrict__ W1,
                                             const float* __restrict__ W2,
                                             const float* __restrict__ Wfc,
                                             __half* __restrict__ Wt) {
    int i = blockIdx.x * 256 + threadIdx.x;
    if (i < 256) gcur[i] = 0u;
    if (i < 3 * 16384) {
        int w = i >> 14, r = i & 16383;
        int nn = r >> 7, kk = r & 127;
        const float* W = (w == 0) ? W1 : (w == 1) ? W2 : Wfc;
        Wt[i] = __float2half(W[kk * 128 + nn]);
    }
}

// MFMA GEMM body (LDS-staged W, measured-good for standalone gemms):
// Y[r,:] = X[r,:] @ W (+bias). 64 rows/block = 4 waves x 16 rows.
template <bool IN_FP32, bool OUT_HALF>
__device__ __forceinline__ void gemm_body(int bx, const void* __restrict__ Xv,
                                          const __half* __restrict__ Wt,
                                          const float* __restrict__ bias,
                                          void* __restrict__ Yv, int n) {
    __shared__ __align__(16) _Float16 Ws[128][136];
    int t = threadIdx.x;
    for (int i = t; i < 2048; i += 256) {   // 2048 x 16B chunks = 128x128 halfs
        int r = i >> 4, c8 = (i & 15) << 3;
        *(f16x8*)&Ws[r][c8] = *(const f16x8*)((const _Float16*)Wt + r * 128 + c8);
    }
    __syncthreads();

    int wave = t >> 6, lane = t & 63;
    int quad = lane >> 4, fcol = lane & 15;
    int rowbase = bx * 64 + wave * 16;
    int arow = rowbase + fcol;

    f16x8 a[4];
#pragma unroll
    for (int c = 0; c < 4; c++) {
        int k0 = c * 32 + quad * 8;
        if (arow < n) {
            if (IN_FP32) {
                const float* p = (const float*)Xv + (size_t)arow * 128 + k0;
#pragma unroll
                for (int j = 0; j < 8; j++) a[c][j] = (_Float16)p[j];
            } else {
                a[c] = *(const f16x8*)((const _Float16*)Xv + (size_t)arow * 128 + k0);
            }
        } else {
            f16x8 z = {0, 0, 0, 0, 0, 0, 0, 0};
            a[c] = z;
        }
    }

    f32x4 acc[8];
#pragma unroll
    for (int c = 0; c < 8; c++) acc[c] = (f32x4){0.f, 0.f, 0.f, 0.f};

#pragma unroll
    for (int kc = 0; kc < 4; kc++) {
        int k0 = kc * 32 + quad * 8;
#pragma unroll
        for (int ct = 0; ct < 8; ct++) {
            f16x8 b = *(const f16x8*)&Ws[ct * 16 + fcol][k0];
            acc[ct] = __builtin_amdgcn_mfma_f32_16x16x32_f16(a[kc], b, acc[ct], 0, 0, 0);
        }
    }

#pragma unroll
    for (int reg = 0; reg < 4; reg++) {
        int gr = rowbase + quad * 4 + reg;
        if (gr < n) {
            if (OUT_HALF) {
                __half* Y = (__half*)Yv;
#pragma unroll
                for (int ct = 0; ct < 8; ct++)
                    Y[(size_t)gr * 128 + ct * 16 + fcol] = __float2half(acc[ct][reg]);
            } else {
                float* Y = (float*)Yv;
#pragma unroll
                for (int ct = 0; ct < 8; ct++)
                    Y[(size_t)gr * 128 + ct * 16 + fcol] = acc[ct][reg] + bias[ct * 16 + fcol];
            }
        }
    }
}

template <bool IN_FP32, bool OUT_HALF>
__global__ __launch_bounds__(256) void k_gemm(const void* __restrict__ Xv,
                                              const __half* __restrict__ Wt,
                                              const float* __restrict__ bias,
                                              void* __restrict__ Yv, int n) {
    gemm_body<IN_FP32, OUT_HALF>(blockIdx.x, Xv, Wt, bias, Yv, n);
}

// LDS-free gemm1 body (R9): B-fragments read straight from global Wt
// (32KB, L1/L2-broadcast across blocks); zero LDS so fused P1 blocks keep
// full occupancy.
__device__ __forceinline__ void gemm1_body_nolds(int bx,
                                                 const float* __restrict__ X,
                                                 const __half* __restrict__ Wt,
                                                 __half* __restrict__ Y, int n) {
    int t = threadIdx.x;
    int wave = t >> 6, lane = t & 63;
    int quad = lane >> 4, fcol = lane & 15;
    int rowbase = bx * 64 + wave * 16;
    int arow = rowbase + fcol;

    f16x8 a[4];
#pragma unroll
    for (int c = 0; c < 4; c++) {
        int k0 = c * 32 + quad * 8;
        if (arow < n) {
            const float* p = X + (size_t)arow * 128 + k0;
#pragma unroll
            for (int j = 0; j < 8; j++) a[c][j] = (_Float16)p[j];
        } else {
            f16x8 z = {0, 0, 0, 0, 0, 0, 0, 0};
            a[c] = z;
        }
    }

    f32x4 acc[8];
#pragma unroll
    for (int c = 0; c < 8; c++) acc[c] = (f32x4){0.f, 0.f, 0.f, 0.f};

#pragma unroll
    for (int kc = 0; kc < 4; kc++) {
        int k0 = kc * 32 + quad * 8;
#pragma unroll
        for (int ct = 0; ct < 8; ct++) {
            f16x8 b = *(const f16x8*)((const _Float16*)Wt +
                                      (size_t)(ct * 16 + fcol) * 128 + k0);
            acc[ct] = __builtin_amdgcn_mfma_f32_16x16x32_f16(a[kc], b, acc[ct], 0, 0, 0);
        }
    }

#pragma unroll
    for (int reg = 0; reg < 4; reg++) {
        int gr = rowbase + quad * 4 + reg;
        if (gr < n) {
#pragma unroll
            for (int ct = 0; ct < 8; ct++)
                Y[(size_t)gr * 128 + ct * 16 + fcol] = __float2half(acc[ct][reg]);
        }
    }
}

// Phase 1: coarse-bin 4096 edges/block by dst>>8. LDS atomics give each
// edge its intra-block rank per bin; ONE global atomic per (block,bin)
// reserves a contiguous run; records written at base+rank.
// Record: bits[0:8)=dst&255, [8:24)=src (N<65536), [32:64)=w bits.
__device__ __forceinline__ void p1_body(int bx, const int* __restrict__ src,
                                        const int* __restrict__ dst,
                                        const float* __restrict__ ew,
                                        unsigned* __restrict__ gcur,
                                        u64* __restrict__ coarse, int E, int NB) {
    __shared__ unsigned lcb[256];    // per-bin count, then per-bin global base
    int t = threadIdx.x;
    lcb[t] = 0u;
    __syncthreads();

    u64 rec[16];
    unsigned br[16];                 // (bin<<16) | rank
    int e0 = bx * 4096 + t;
#pragma unroll
    for (int k = 0; k < 16; k++) {
        int e = e0 + k * 256;
        if (e < E) {
            int d = dst[e];
            int s = src[e];
            unsigned wb = __float_as_uint(ew[e]);
            int bin = d >> 8;
            unsigned r = atomicAdd(&lcb[bin], 1u);   // LDS atomic
            rec[k] = ((u64)wb << 32) | ((u64)((unsigned)s << 8)) | (u64)(d & 255);
            br[k] = ((unsigned)bin << 16) | r;       // rank < 4096 fits
        } else {
            br[k] = 0xFFFFFFFFu;
        }
    }
    __syncthreads();
    if (t < NB) {
        unsigned c = lcb[t];
        unsigned base = c ? atomicAdd(&gcur[t], c) : 0u;  // 1 global atomic/bin
        lcb[t] = base;
    }
    __syncthreads();
#pragma unroll
    for (int k = 0; k < 16; k++) {
        if (br[k] != 0xFFFFFFFFu) {
            int bin = br[k] >> 16;
            unsigned pos = lcb[bin] + (br[k] & 0xFFFFu);
            if (pos < CREG)
                coarse[(size_t)bin * CREG + pos] = rec[k];
        }
    }
}

// Fused launch: blocks [0,GB) = LDS-free gemm1, blocks [GB, GB+p1b) = P1.
__global__ __launch_bounds__(256) void k_gemm1_p1(
    const float* __restrict__ x, const __half* __restrict__ Wt,
    __half* __restrict__ bufH, int n, int GB,
    const int* __restrict__ src, const int* __restrict__ dst,
    const float* __restrict__ ew, unsigned* __restrict__ gcur,
    u64* __restrict__ coarse, int E, int NB) {
    int bx = blockIdx.x;
    if (bx < GB) {
        gemm1_body_nolds(bx, x, Wt, bufH, n);
        return;
    }
    p1_body(bx - GB, src, dst, ew, gcur, coarse, E, NB);
}

// Phase 2: one block per bucket (256 nodes). Coalesced read of the bucket's
// records; LDS cursors (no global atomics) scatter into slots; LDS float
// sums -> cnt + dinv written directly.
__global__ __launch_bounds__(256) void k_build(const u64* __restrict__ coarse,
                                               const unsigned* __restrict__ gcur,
                                               int2* __restrict__ slots,
                                               unsigned* __restrict__ cnt,
                                               float* __restrict__ dinv,
                                               int n) {
    __shared__ unsigned lcnt[256];
    __shared__ float lws[256];
    int b = blockIdx.x, t = threadIdx.x;
    lcnt[t] = 0u;
    lws[t] = 0.f;
    __syncthreads();
    int ec = min((int)gcur[b], CREG);
    const u64* reg = coarse + (size_t)b * CREG;
    int nb0 = b << 8;
    for (int e = t; e < ec; e += 256) {
        u64 r = reg[e];
        int dloc = (int)(r & 255u);
        int s = (int)((r >> 8) & 0xFFFFu);
        unsigned wb = (unsigned)(r >> 32);
        unsigned pos = atomicAdd(&lcnt[dloc], 1u);        // LDS atomic
        atomicAdd(&lws[dloc], __uint_as_float(wb));       // LDS float atomic
        if (pos < CAP)
            slots[(size_t)(nb0 + dloc) * CAP + pos] = make_int2(s, (int)wb);
    }
    __syncthreads();
    int node = nb0 + t;
    if (node < n) {
        cnt[node] = lcnt[t];
        dinv[node] = rsqrtf(1.0f + lws[t]);
    }
}

// R15 k_agg: one wave per node; TWO rows per gather instruction.
// lane = hi*32 + c32: lanes 0-31 read row of edge e (8B = 4 halfs at
// feature c32*4), lanes 32-63 read row of edge e+1. Each lane accumulates
// 4 features (fp32) of its edge-half; final shfl_xor(32) merges halves.
// Coop phase unchanged: lane-parallel slot load + dinv gather, shfl bcast.
__global__ __launch_bounds__(256) void k_agg(const __half* __restrict__ H,
                                             const int2* __restrict__ slots,
                                             const unsigned* __restrict__ cnt,
                                             const float* __restrict__ dinv,
                                             const float* __restrict__ bias,
                                             __half* __restrict__ out, int n) {
    int wid = (blockIdx.x * 256 + threadIdx.x) >> 6;
    int lane = threadIdx.x & 63;
    if (wid >= n) return;
    int i = __builtin_amdgcn_readfirstlane(wid);  // wave-uniform -> scalar loads
    int c32 = lane & 31, hi = lane >> 5;
    float di = dinv[i];

    float acc0 = 0.f, acc1 = 0.f, acc2 = 0.f, acc3 = 0.f;
    {   // self term: hi==0 half only (merge adds hi==1's zero)
        uint2 q = ((const uint2*)(H + (size_t)i * 128))[c32];
        float2 f0 = __half22float2(*(__half2*)&q.x);
        float2 f1 = __half22float2(*(__half2*)&q.y);
        if (hi == 0) {
            float dd = di * di;
            acc0 = dd * f0.x; acc1 = dd * f0.y;
            acc2 = dd * f1.x; acc3 = dd * f1.y;
        }
    }
    int c = min((int)cnt[i], CAP);
    const int2* row = slots + (size_t)i * CAP;

    for (int base = 0; base < c; base += 64) {
        int cnt2 = min(64, c - base);
        int mys = 0; float myv = 0.f;
        if (lane < cnt2) {
            int2 pr = row[base + lane];
            mys = pr.x;
            myv = dinv[pr.x] * __int_as_float(pr.y) * di;
        }
        int j = 0;
        for (; j + 16 <= cnt2; j += 16) {   // 16 edges = 8 paired gathers
            uint2 q[8]; float vv[8];
#pragma unroll
            for (int u = 0; u < 8; u++) {
                int s0 = __shfl(mys, j + 2 * u);
                int s1 = __shfl(mys, j + 2 * u + 1);
                float v0 = __shfl(myv, j + 2 * u);
                float v1 = __shfl(myv, j + 2 * u + 1);
                int s = hi ? s1 : s0;
                vv[u] = hi ? v1 : v0;
                q[u] = ((const uint2*)(H + (size_t)s * 128))[c32];
            }
#pragma unroll
            for (int u = 0; u < 8; u++) {
                float2 f0 = __half22float2(*(__half2*)&q[u].x);
                float2 f1 = __half22float2(*(__half2*)&q[u].y);
                acc0 = fmaf(vv[u], f0.x, acc0);
                acc1 = fmaf(vv[u], f0.y, acc1);
                acc2 = fmaf(vv[u], f1.x, acc2);
                acc3 = fmaf(vv[u], f1.y, acc3);
            }
        }
        for (; j < cnt2; j += 8) {          // masked tail: 8 edges = 4 gathers
            uint2 q[4]; float vv[4];
#pragma unroll
            for (int u = 0; u < 4; u++) {
                int i0 = j + 2 * u, i1 = i0 + 1;
                int l0 = min(i0, cnt2 - 1), l1 = min(i1, cnt2 - 1);
                int s0 = __shfl(mys, l0);
                int s1 = __shfl(mys, l1);
                float v0 = __shfl(myv, l0);
                float v1 = __shfl(myv, l1);
                v0 = (i0 < cnt2) ? v0 : 0.f;
                v1 = (i1 < cnt2) ? v1 : 0.f;
                int s = hi ? s1 : s0;
                vv[u] = hi ? v1 : v0;
                q[u] = ((const uint2*)(H + (size_t)s * 128))[c32];
            }
#pragma unroll
            for (int u = 0; u < 4; u++) {
                float2 f0 = __half22float2(*(__half2*)&q[u].x);
                float2 f1 = __half22float2(*(__half2*)&q[u].y);
                acc0 = fmaf(vv[u], f0.x, acc0);
                acc1 = fmaf(vv[u], f0.y, acc1);
                acc2 = fmaf(vv[u], f1.x, acc2);
                acc3 = fmaf(vv[u], f1.y, acc3);
            }
        }
    }
    // merge the two edge-halves
    acc0 += __shfl_xor(acc0, 32);
    acc1 += __shfl_xor(acc1, 32);
    acc2 += __shfl_xor(acc2, 32);
    acc3 += __shfl_xor(acc3, 32);
    if (hi == 0) {                          // lanes 0-31 write 8B each (256B row)
        float4 b4 = ((const float4*)bias)[c32];
        acc0 = fmaxf(acc0 + b4.x, 0.f);
        acc1 = fmaxf(acc1 + b4.y, 0.f);
        acc2 = fmaxf(acc2 + b4.z, 0.f);
        acc3 = fmaxf(acc3 + b4.w, 0.f);
        uint2 o;
        *(__half2*)&o.x = __floats2half2_rn(acc0, acc1);
        *(__half2*)&o.y = __floats2half2_rn(acc2, acc3);
        ((uint2*)(out + (size_t)i * 128))[c32] = o;
    }
}

extern "C" void kernel_launch(void* const* d_in, const int* in_sizes, int n_in,
                              void* d_out, int out_size, void* d_ws, size_t ws_size,
                              hipStream_t stream) {
    const float* x   = (const float*)d_in[0];
    const float* ew  = (const float*)d_in[1];
    const float* W1  = (const float*)d_in[2];
    const float* b1  = (const float*)d_in[3];
    const float* W2  = (const float*)d_in[4];
    const float* b2  = (const float*)d_in[5];
    const float* Wfc = (const float*)d_in[6];
    const float* bfc = (const float*)d_in[7];
    const int* eidx  = (const int*)d_in[8];

    const int E = in_sizes[1];
    const int N = in_sizes[0] / 128;
    const int* src = eidx;       // edge_index row 0
    const int* dst = eidx + E;   // edge_index row 1

    char* ws = (char*)d_ws;
    size_t off = 0;
    auto alloc = [&](size_t bytes) -> void* {
        void* p = ws + off;
        off = (off + bytes + 255) & ~(size_t)255;
        return p;
    };
    int gb  = (N + 63) / 64;             // MFMA gemm: 64 rows/block
    int p1b = (E + 4095) / 4096;         // P1: 4096 edges/block
    int NB  = (N + 255) >> 8;            // coarse buckets of 256 nodes
    int ab  = (N * 64 + 255) / 256;      // wave-per-node agg
    int pb  = (3 * 16384 + 255) / 256;
    int Npad = N + 64;

    unsigned* gcur = (unsigned*)alloc(256 * 4);
    unsigned* cnt  = (unsigned*)alloc((size_t)N * 4);
    float*  dinv   = (float*)alloc((size_t)N * 4);
    u64*    coarse = (u64*)alloc((size_t)NB * CREG * 8);
    int2*   slots  = (int2*)alloc((size_t)N * CAP * 8);
    __half* Wt     = (__half*)alloc((size_t)3 * 16384 * 2);  // 3 fp16 [n][k]
    __half* bufH   = (__half*)alloc((size_t)Npad * 128 * 2); // gemm output
    __half* bufA   = (__half*)alloc((size_t)Npad * 128 * 2); // agg output

    // Prep: zero cursors + weight transpose; then gemm1 fused with P1.
    k_pre<<<pb, 256, 0, stream>>>(gcur, W1, W2, Wfc, Wt);
    k_gemm1_p1<<<gb + p1b, 256, 0, stream>>>(x, Wt, bufH, N, gb,
                                             src, dst, ew, gcur, coarse, E, NB);
    k_build<<<NB, 256, 0, stream>>>(coarse, gcur, slots, cnt, dinv, N);

    // Layer 1 aggregation
    k_agg<<<ab, 256, 0, stream>>>(bufH, slots, cnt, dinv, b1, bufA, N);
    // Layer 2
    k_gemm<false, true><<<gb, 256, 0, stream>>>(bufA, Wt + 16384, nullptr, bufH, N);
    k_agg<<<ab, 256, 0, stream>>>(bufH, slots, cnt, dinv, b2, bufA, N);
    // FC: fp16 in, fp32 out + bias to d_out
    k_gemm<false, false><<<gb, 256, 0, stream>>>(bufA, Wt + 2 * 16384, bfc, d_out, N);
}